// Round 7
// baseline (84.227 us; speedup 1.0000x reference)
//
#include <hip/hip_runtime.h>
#include <stdint.h>

namespace {

constexpr int   B_    = 64;
constexpr int   F0_   = 1876;
constexpr int   F1_   = 1024;
constexpr int   F2_   = 10;
constexpr int   NT_   = 151;
constexpr float DT_   = 0.02f;
constexpr int   NB1_  = 51;       // real bins 0..50
constexpr int   NSTR_ = 2688;     // padded stream capacity = 336 groups of 8
constexpr int   NGT_  = 336;      // groups total
constexpr int   GPW_  = 42;       // groups per wave (8 waves)
constexpr int   ROWB_ = 4096;     // W1Tp row stride bytes
constexpr float SCL_  = 67108864.0f;        // 2^26 fixed-point scale
constexpr float ISCL_ = 1.0f / 67108864.0f;

// workspace layout (bytes)
constexpr size_t OFF_W1T  = 0;                       // 1877*1024*4 = 7,688,192
constexpr size_t OFF_PAIR = 7688192;                 // 64*2688*8   = 1,376,256
constexpr size_t OFF_GB   = OFF_PAIR + 1376256;      // 64*336*4    =    86,016
constexpr size_t OFF_IDX1 = OFF_GB + 86016;          // 64*1024 u8  =    65,536

// ---------------------------------------------------------------------------
// k_prep: fused  (a) W1 -> column-permuted transpose W1Tp  (blocks 0..479)
//                (b) per-b padded counting sort of ti       (blocks 480..543)
// Permutation: within jp-slice of 128 cols, pc = 2*(r&63) + (r>>6), r=j&127,
// so a lane's float2 at pc=2*lane covers j0=jp*128+lane, j1=jp*128+64+lane.
// Sort pads every bin-run to a multiple of 8 (dummy row 1876 = zeros) and
// emits per-group headers gB[b][g] = bin of group g (80 for tail groups).
// ---------------------------------------------------------------------------
__global__ __launch_bounds__(256) void k_prep(const float* __restrict__ W1,
                                              const float* __restrict__ ti,
                                              float* __restrict__ W1Tp,
                                              uint2* __restrict__ sPair,
                                              uint32_t* __restrict__ gB) {
  __shared__ uint32_t smem[13184];
  const int t = threadIdx.x;
  if (blockIdx.x < 480) {
    float (*tile)[65] = (float (*)[65])smem;
    const int bx = blockIdx.x;
    const int i0 = (bx % 30) * 64;     // rows 0..1919
    const int j0 = (bx / 30) * 64;
    const int c = t & 63, r4 = t >> 6;
    for (int jj = r4; jj < 64; jj += 4) {
      int i = i0 + c;
      tile[c][jj] = (i < F0_) ? W1[(size_t)(j0 + jj) * F0_ + i] : 0.0f;
    }
    __syncthreads();
    for (int ii = r4; ii < 64; ii += 4) {
      int i = i0 + ii;
      if (i <= F0_) {
        int j = j0 + c;
        int jp = j >> 7, r = j & 127;
        int pc = (jp << 7) + ((r & 63) << 1) + (r >> 6);
        W1Tp[(size_t)i * F1_ + pc] = tile[ii][c];
      }
    }
  } else {
    uint32_t (*hist)[NB1_] = (uint32_t (*)[NB1_])smem;   // [256][51]
    uint32_t* pstart = smem + 256 * NB1_;                // [52]
    uint32_t* cnts   = pstart + 52;                      // [51]
    const int b = blockIdx.x - 480;
    for (int k = 0; k < NB1_; ++k) hist[t][k] = 0;
    __syncthreads();

    const float* tib = ti + (size_t)b * F0_;
    const int n0 = t * 8, n1 = (n0 + 8 < F0_) ? n0 + 8 : F0_;
    for (int n = n0; n < n1; ++n) {
      int k = (int)ceilf(tib[n] * 50.0f);
      k = k < 0 ? 0 : (k > 50 ? 50 : k);
      hist[t][k]++;
    }
    __syncthreads();

    if (t < NB1_) {                 // exclusive prefix over 256 chunks per bin
      uint32_t run = 0;
      for (int c = 0; c < 256; ++c) { uint32_t x = hist[c][t]; hist[c][t] = run; run += x; }
      cnts[t] = run;
    }
    __syncthreads();
    if (t == 0) {                   // padded bin starts (multiples of 8)
      uint32_t acc = 0;
      pstart[0] = 0;
      for (int k = 0; k < NB1_; ++k) {
        acc += (cnts[k] + 7u) & ~7u;
        pstart[k + 1] = acc;
      }
    }
    __syncthreads();

    const uint32_t PT = pstart[NB1_];            // padded total (mult of 8)
    uint2*    out = sPair + (size_t)b * NSTR_;
    uint32_t* gb  = gB + (size_t)b * NGT_;
    const uint2 dummy = make_uint2((uint32_t)F0_ * (uint32_t)ROWB_, 0u);

    for (int n = n0; n < n1; ++n) {              // stable scatter
      float v = tib[n];
      int k = (int)ceilf(v * 50.0f);
      k = k < 0 ? 0 : (k > 50 ? 50 : k);
      uint32_t pos = pstart[k] + hist[t][k]++;
      out[pos] = make_uint2((uint32_t)n * (uint32_t)ROWB_, __float_as_uint(v));
    }
    if (t < NB1_) {                              // in-bin pads + headers
      uint32_t s0 = pstart[t] + cnts[t], s1 = pstart[t + 1];
      for (uint32_t s = s0; s < s1; ++s) out[s] = dummy;
      for (uint32_t g = pstart[t] >> 3; g < (s1 >> 3); ++g) gb[g] = (uint32_t)t;
    }
    for (uint32_t s = PT + t; s < (uint32_t)NSTR_; s += 256) out[s] = dummy;
    for (uint32_t g = (PT >> 3) + t; g < (uint32_t)NGT_; g += 256) gb[g] = 80u;
  }
}

// ---------------------------------------------------------------------------
// Layer-1 main: 512 blocks = (b major, jp minor -> XCD=jp), 8 waves of 64.
// Pairs+headers staged in LDS; every 8-group is bin-uniform (padded sort) so
// the inner loop is pure {4 ds_read_b128, 8 v_add+load, 32 fma/add} with ONE
// scalar header compare per group. Register (SA,SC) per lane for 2 j's;
// per-bin deltas dumped at (rare, uniform) group transitions as fixed-point
// int32 LDS atomics (order-independent -> deterministic).
// Phase 2: prefix over bins, (t-quarter, j-half) per wave, min-reduce.
// ---------------------------------------------------------------------------
__global__ __launch_bounds__(512, 4) void k_main1(const uint2* __restrict__ sPair,
                                                  const uint32_t* __restrict__ gB,
                                                  const float* __restrict__ W1Tp,
                                                  uint8_t* __restrict__ idx1) {
  __shared__ uint2    pr[NSTR_];        // 21504 B
  __shared__ uint32_t gbw[NGT_];        //  1344 B
  __shared__ int binAi[NB1_][128];      // 26112 B
  __shared__ int binCi[NB1_][128];      // 26112 B
  __shared__ int cand[4][128];          //  2048 B
  const int blk  = blockIdx.x;          // 512
  const int b    = blk >> 3;
  const int jp   = blk & 7;
  const int tid  = threadIdx.x;
  const int lane = tid & 63;
  const int wv   = __builtin_amdgcn_readfirstlane(tid >> 6);  // 0..7

  {
    const uint4* src = (const uint4*)(sPair + (size_t)b * NSTR_);
    uint4* dst = (uint4*)pr;
    for (int s = tid; s < NSTR_ / 2; s += 512) dst[s] = src[s];
    const uint32_t* gsrc = gB + (size_t)b * NGT_;
    for (int s = tid; s < NGT_; s += 512) gbw[s] = gsrc[s];
    int4* p = (int4*)(&binAi[0][0]);
    for (int s = tid; s < (NB1_ * 128 * 2) / 4; s += 512) p[s] = make_int4(0, 0, 0, 0);
  }
  __syncthreads();

  const char* wb = (const char*)W1Tp;
  const uint32_t col8 = (uint32_t)(jp * 512 + lane * 8);
  const int g0 = wv * GPW_;

  float SA0 = 0.f, SC0 = 0.f, SA1 = 0.f, SC1 = 0.f;
  float SA0p = 0.f, SC0p = 0.f, SA1p = 0.f, SC1p = 0.f;
  uint32_t kcur;

  uint32_t rA[8], rB[8], rC[8], hA, hB, hC;
  float    tA[8], tB[8], tC[8];
  float2   WA[8], WB[8], WC[8];

#define LOADP(S, g) { const int gg = (g) <= (NGT_ - 1) ? (g) : (NGT_ - 1);    \
  _Pragma("unroll") for (int q = 0; q < 4; ++q) {                             \
    uint4 x = *(const uint4*)(&pr[gg * 8 + q * 2]);                           \
    r##S[2 * q]     = x.x; t##S[2 * q]     = __uint_as_float(x.y);            \
    r##S[2 * q + 1] = x.z; t##S[2 * q + 1] = __uint_as_float(x.w); }          \
  h##S = gbw[gg]; }

#define ISSW(S) { _Pragma("unroll") for (int e = 0; e < 8; ++e)               \
    W##S[e] = *(const float2*)(wb + (size_t)(r##S[e] + col8)); }

#define DUMP() { if (kcur < (uint32_t)NB1_) {                                 \
    atomicAdd(&binAi[kcur][lane],      __float2int_rn((SA0 - SA0p) * SCL_));  \
    atomicAdd(&binCi[kcur][lane],      __float2int_rn((SC0 - SC0p) * SCL_));  \
    atomicAdd(&binAi[kcur][64 + lane], __float2int_rn((SA1 - SA1p) * SCL_));  \
    atomicAdd(&binCi[kcur][64 + lane], __float2int_rn((SC1 - SC1p) * SCL_)); }\
  SA0p = SA0; SC0p = SC0; SA1p = SA1; SC1p = SC1; }

#define PROC(S) {                                                             \
  uint32_t kg = __builtin_amdgcn_readfirstlane(h##S);                         \
  if (kg != kcur) { DUMP(); kcur = kg; }                                      \
  _Pragma("unroll") for (int e = 0; e < 8; ++e) {                             \
    SA0 += W##S[e].x; SC0 = fmaf(W##S[e].x, t##S[e], SC0);                    \
    SA1 += W##S[e].y; SC1 = fmaf(W##S[e].y, t##S[e], SC1); } }

  // prologue: pairs 2 groups deep, weights 2 groups deep
  LOADP(A, g0); LOADP(B, g0 + 1);
  ISSW(A); ISSW(B);
  kcur = __builtin_amdgcn_readfirstlane(hA);

#pragma unroll 1
  for (int m = 0; m < GPW_ / 3; ++m) {           // 14 iters, 3 groups each
    const int g = g0 + 3 * m;
    LOADP(C, g + 2); PROC(A); ISSW(C);
    LOADP(A, g + 3); PROC(B); ISSW(A);
    LOADP(B, g + 4); PROC(C); ISSW(B);
  }
  DUMP();        // final delta (skipped if kcur is dummy bin 80)

#undef PROC
#undef DUMP
#undef ISSW
#undef LOADP

  __syncthreads();

  // phase 2: prefix over bins; wave wv = (tq<<1)|jh checks col jh*64+lane
  {
    const int jh = wv & 1, tq = wv >> 1;
    const int col = jh * 64 + lane;
    float SA2 = 0.f, SC2 = 0.f;
    int cnd = 151;
    const int t0 = tq * 38;
    const int t1 = (tq == 3) ? NT_ : t0 + 38;
    for (int tt = 0; tt < t1; ++tt) {
      if (tt < NB1_) {
        SA2 += (float)binAi[tt][col] * ISCL_;
        SC2 += (float)binCi[tt][col] * ISCL_;
      }
      if (tt >= t0 && cnd == 151) {
        float m = (float)tt * DT_ * SA2 - SC2;
        if (m >= 1.0f) cnd = tt;
      }
    }
    cand[tq][col] = cnd;
  }
  __syncthreads();
  if (tid < 128) {
    int id = min(min(cand[0][tid], cand[1][tid]),
                 min(cand[2][tid], cand[3][tid]));
    id = min(id, NT_ - 1);               // forced spike at last timestep
    idx1[((size_t)b << 10) + (jp << 7) + tid] = (uint8_t)id;
  }
}

// ---------------------------------------------------------------------------
// Layer-2: brute force. Block = (b,j), 4 waves split the i-range; lane = t.
// ---------------------------------------------------------------------------
__global__ __launch_bounds__(256) void k_main2(const uint8_t* __restrict__ idx1,
                                               const float* __restrict__ W2,
                                               float* __restrict__ out) {
  __shared__ float wrow[F1_];
  __shared__ float tirow[F1_];
  __shared__ float part[4][3][64];
  const int blk = blockIdx.x;          // 640
  const int b   = blk / 10;
  const int j   = blk - b * 10;
  const int tid = threadIdx.x;
  const int lane = tid & 63, wvv = tid >> 6;

  const float*   w = W2  + (size_t)j * F1_;
  const uint8_t* h = idx1 + (size_t)b * F1_;
  for (int s = tid; s < F1_; s += 256) {
    wrow[s]  = w[s];
    tirow[s] = (float)h[s] * DT_;
  }
  __syncthreads();

  const float tl0 = (float)lane * DT_;
  const float tl1 = (float)(lane + 64) * DT_;
  const float tl2 = (float)(lane + 128) * DT_;
  float m0 = 0.f, m1 = 0.f, m2 = 0.f;
  const int i0 = wvv * 256;
#pragma unroll 4
  for (int i = i0; i < i0 + 256; ++i) {
    float tiv = tirow[i], ww = wrow[i];
    m0 = fmaf(ww, fmaxf(tl0 - tiv, 0.f), m0);
    m1 = fmaf(ww, fmaxf(tl1 - tiv, 0.f), m1);
    m2 = fmaf(ww, fmaxf(tl2 - tiv, 0.f), m2);
  }
  part[wvv][0][lane] = m0;
  part[wvv][1][lane] = m1;
  part[wvv][2][lane] = m2;
  __syncthreads();

  if (wvv == 0) {
    m0 = part[0][0][lane] + part[1][0][lane] + part[2][0][lane] + part[3][0][lane];
    m1 = part[0][1][lane] + part[1][1][lane] + part[2][1][lane] + part[3][1][lane];
    m2 = part[0][2][lane] + part[1][2][lane] + part[2][2][lane] + part[3][2][lane];
    unsigned long long b0 = __ballot(m0 >= 1.0f);
    unsigned long long b1 = __ballot(m1 >= 1.0f);
    unsigned long long b2 = __ballot(m2 >= 1.0f);
    b2 &= (1ull << 23) - 1;            // t <= 150
    b2 |= (1ull << 22);                // forced spike at t = 150
    int tres;
    if (b0)      tres = __ffsll((long long)b0) - 1;
    else if (b1) tres = 64 + __ffsll((long long)b1) - 1;
    else         tres = 128 + __ffsll((long long)b2) - 1;
    if (lane == 0) out[(size_t)b * F2_ + j] = (float)tres * DT_;
  }
}

}  // namespace

// ---------------------------------------------------------------------------
extern "C" void kernel_launch(void* const* d_in, const int* in_sizes, int n_in,
                              void* d_out, int out_size, void* d_ws, size_t ws_size,
                              hipStream_t stream) {
  const float* ti = (const float*)d_in[0];   // [64][1876]
  const float* W1 = (const float*)d_in[1];   // [1024][1876]
  const float* W2 = (const float*)d_in[2];   // [10][1024]
  float* out = (float*)d_out;                // [64][10]

  char* ws = (char*)d_ws;
  float*    W1Tp = (float*)(ws + OFF_W1T);
  uint2*    sPr  = (uint2*)(ws + OFF_PAIR);
  uint32_t* gBp  = (uint32_t*)(ws + OFF_GB);
  uint8_t*  idx1 = (uint8_t*)(ws + OFF_IDX1);

  hipLaunchKernelGGL(k_prep,  dim3(544), dim3(256), 0, stream, W1, ti, W1Tp, sPr, gBp);
  hipLaunchKernelGGL(k_main1, dim3(512), dim3(512), 0, stream, sPr, gBp, W1Tp, idx1);
  hipLaunchKernelGGL(k_main2, dim3(640), dim3(256), 0, stream, idx1, W2, out);
}

// Round 8
// 73.880 us; speedup vs baseline: 1.1400x; 1.1400x over previous
//
#include <hip/hip_runtime.h>
#include <stdint.h>

namespace {

constexpr int   B_    = 64;
constexpr int   F0_   = 1876;
constexpr int   F1_   = 1024;
constexpr int   F2_   = 10;
constexpr int   NT_   = 151;
constexpr float DT_   = 0.02f;
constexpr int   NB1_  = 51;       // real bins 0..50
constexpr int   NSTR_ = 2688;     // padded stream capacity = 336 groups of 8
constexpr int   NGT_  = 336;      // group capacity
constexpr int   ROWB_ = 4096;     // W1T row stride bytes
constexpr float SCL_  = 67108864.0f;        // 2^26 fixed-point scale
constexpr float ISCL_ = 1.0f / 67108864.0f;

// workspace layout (bytes)
constexpr size_t OFF_W1T  = 0;                       // 1877*1024*4 = 7,688,192
constexpr size_t OFF_PAIR = 7688192;                 // 64*2688*8   = 1,376,256
constexpr size_t OFF_GB   = OFF_PAIR + 1376256;      // 64*336*4    =    86,016
constexpr size_t OFF_GNG  = OFF_GB + 86016;          // 64*4        =       256
constexpr size_t OFF_IDX1 = OFF_GNG + 256;           // 64*1024 u8  =    65,536

// ---------------------------------------------------------------------------
// k_prep: fused  (a) W1 -> plain transpose W1T (blocks 0..479)
//                (b) per-b padded counting sort of ti (blocks 480..543)
// Sort pads every bin-run to a multiple of 8 (dummy row 1876 = zeros), emits
// per-group headers gB[b][g] (bin id; 80 for dummy/tail) and the real padded
// group count gNG[b].
// ---------------------------------------------------------------------------
__global__ __launch_bounds__(256) void k_prep(const float* __restrict__ W1,
                                              const float* __restrict__ ti,
                                              float* __restrict__ W1T,
                                              uint2* __restrict__ sPair,
                                              uint32_t* __restrict__ gB,
                                              uint32_t* __restrict__ gNG) {
  __shared__ uint32_t smem[13184];
  const int t = threadIdx.x;
  if (blockIdx.x < 480) {
    float (*tile)[65] = (float (*)[65])smem;
    const int bx = blockIdx.x;
    const int i0 = (bx % 30) * 64;     // rows 0..1919
    const int j0 = (bx / 30) * 64;
    const int c = t & 63, r4 = t >> 6;
    for (int jj = r4; jj < 64; jj += 4) {
      int i = i0 + c;
      tile[c][jj] = (i < F0_) ? W1[(size_t)(j0 + jj) * F0_ + i] : 0.0f;
    }
    __syncthreads();
    for (int ii = r4; ii < 64; ii += 4) {
      int i = i0 + ii;
      if (i <= F0_) W1T[(size_t)i * F1_ + j0 + c] = tile[ii][c];
    }
  } else {
    uint32_t (*hist)[NB1_] = (uint32_t (*)[NB1_])smem;   // [256][51]
    uint32_t* pstart = smem + 256 * NB1_;                // [52]
    uint32_t* cnts   = pstart + 52;                      // [51]
    const int b = blockIdx.x - 480;
    for (int k = 0; k < NB1_; ++k) hist[t][k] = 0;
    __syncthreads();

    const float* tib = ti + (size_t)b * F0_;
    const int n0 = t * 8, n1 = (n0 + 8 < F0_) ? n0 + 8 : F0_;
    for (int n = n0; n < n1; ++n) {
      int k = (int)ceilf(tib[n] * 50.0f);
      k = k < 0 ? 0 : (k > 50 ? 50 : k);
      hist[t][k]++;
    }
    __syncthreads();

    if (t < NB1_) {                 // exclusive prefix over 256 chunks per bin
      uint32_t run = 0;
      for (int c = 0; c < 256; ++c) { uint32_t x = hist[c][t]; hist[c][t] = run; run += x; }
      cnts[t] = run;
    }
    __syncthreads();
    if (t == 0) {                   // padded bin starts (multiples of 8)
      uint32_t acc = 0;
      pstart[0] = 0;
      for (int k = 0; k < NB1_; ++k) {
        acc += (cnts[k] + 7u) & ~7u;
        pstart[k + 1] = acc;
      }
      gNG[b] = acc >> 3;            // real padded group count
    }
    __syncthreads();

    const uint32_t PT = pstart[NB1_];            // padded total (mult of 8)
    uint2*    out = sPair + (size_t)b * NSTR_;
    uint32_t* gb  = gB + (size_t)b * NGT_;
    const uint2 dummy = make_uint2((uint32_t)F0_ * (uint32_t)ROWB_, 0u);

    for (int n = n0; n < n1; ++n) {              // stable scatter
      float v = tib[n];
      int k = (int)ceilf(v * 50.0f);
      k = k < 0 ? 0 : (k > 50 ? 50 : k);
      uint32_t pos = pstart[k] + hist[t][k]++;
      out[pos] = make_uint2((uint32_t)n * (uint32_t)ROWB_, __float_as_uint(v));
    }
    if (t < NB1_) {                              // in-bin pads + headers
      uint32_t s0 = pstart[t] + cnts[t], s1 = pstart[t + 1];
      for (uint32_t s = s0; s < s1; ++s) out[s] = dummy;
      for (uint32_t g = pstart[t] >> 3; g < (s1 >> 3); ++g) gb[g] = (uint32_t)t;
    }
    for (uint32_t s = PT + t; s < (uint32_t)NSTR_; s += 256) out[s] = dummy;
    for (uint32_t g = (PT >> 3) + t; g < (uint32_t)NGT_; g += 256) gb[g] = 80u;
  }
}

// ---------------------------------------------------------------------------
// Layer-1 main: 1024 blocks = (b major, jp minor; 16 slices of 64 j), 8 waves
// of 64.  Pairs+headers staged in LDS; every 8-group is bin-uniform so the
// inner loop is branch-free per element.  Depth-2 weight pipeline PINNED with
// sched_barrier(0) so hipcc cannot sink the prefetch loads to their uses
// (r6/r7 VGPR=44 proved it did, exposing full L2 latency per group).
// Waves split the real [0,NG) group range evenly (no dummy-tail work).
// Per-bin (SA,SC) deltas dumped at (rare, uniform) bin transitions as
// fixed-point int32 LDS atomics (order-independent -> deterministic).
// Phase 2: prefix over bins, 8 t-ranges, min-reduce.  LDS 51 KB -> 3 blk/CU.
// ---------------------------------------------------------------------------
__global__ __launch_bounds__(512, 6) void k_main1(const uint2* __restrict__ sPair,
                                                  const uint32_t* __restrict__ gB,
                                                  const uint32_t* __restrict__ gNG,
                                                  const float* __restrict__ W1T,
                                                  uint8_t* __restrict__ idx1) {
  __shared__ uint2    pr[NSTR_];        // 21504 B
  __shared__ uint32_t gbw[NGT_];        //  1344 B
  __shared__ int binAi[NB1_][64];       // 13056 B
  __shared__ int binCi[NB1_][64];       // 13056 B
  __shared__ int cand[8][64];           //  2048 B
  const int blk  = blockIdx.x;          // 1024
  const int b    = blk >> 4;
  const int jp   = blk & 15;
  const int tid  = threadIdx.x;
  const int lane = tid & 63;
  const int wv   = __builtin_amdgcn_readfirstlane(tid >> 6);  // 0..7

  {
    const uint4* src = (const uint4*)(sPair + (size_t)b * NSTR_);
    uint4* dst = (uint4*)pr;
    for (int s = tid; s < NSTR_ / 2; s += 512) dst[s] = src[s];
    const uint32_t* gsrc = gB + (size_t)b * NGT_;
    for (int s = tid; s < NGT_; s += 512) gbw[s] = gsrc[s];
    int4* p = (int4*)(&binAi[0][0]);
    for (int s = tid; s < (NB1_ * 64 * 2) / 4; s += 512) p[s] = make_int4(0, 0, 0, 0);
  }
  __syncthreads();

  const uint32_t NG = gNG[b];                    // uniform (~235..262)
  const int q  = (int)(NG >> 3), rr = (int)(NG & 7);
  const int g0  = wv * q + (wv < rr ? wv : rr);
  const int cnt = q + (wv < rr ? 1 : 0);

  const char* wb = (const char*)W1T;
  const uint32_t col4 = (uint32_t)((jp << 6) + lane) * 4u;

  float SA = 0.f, SC = 0.f, SAp = 0.f, SCp = 0.f;
  uint32_t kcur;

  uint32_t rA[8], rB[8], hA, hB;
  float    tA[8], tB[8];
  float    WA[8], WB[8];

#define LOADP(S, g) { const int gg = (g) <= (NGT_ - 1) ? (g) : (NGT_ - 1);    \
  _Pragma("unroll") for (int q2 = 0; q2 < 4; ++q2) {                          \
    uint4 x = *(const uint4*)(&pr[gg * 8 + q2 * 2]);                          \
    r##S[2 * q2]     = x.x; t##S[2 * q2]     = __uint_as_float(x.y);          \
    r##S[2 * q2 + 1] = x.z; t##S[2 * q2 + 1] = __uint_as_float(x.w); }        \
  h##S = gbw[gg]; }

#define ISSW(S) { _Pragma("unroll") for (int e = 0; e < 8; ++e)               \
    W##S[e] = *(const float*)(wb + (size_t)(r##S[e] + col4)); }

#define DUMP() { if (kcur < (uint32_t)NB1_) {                                 \
    atomicAdd(&binAi[kcur][lane], __float2int_rn((SA - SAp) * SCL_));         \
    atomicAdd(&binCi[kcur][lane], __float2int_rn((SC - SCp) * SCL_)); }       \
  SAp = SA; SCp = SC; }

#define PROC(S) {                                                             \
  uint32_t kg = __builtin_amdgcn_readfirstlane(h##S);                         \
  if (kg != kcur) { DUMP(); kcur = kg; }                                      \
  _Pragma("unroll") for (int e = 0; e < 8; ++e) {                             \
    SA += W##S[e]; SC = fmaf(W##S[e], t##S[e], SC); } }

// prefetch group g into Snxt, FENCE, then consume Scur
#define STEP(Scur, Snxt, g)                                                   \
  LOADP(Snxt, g); ISSW(Snxt);                                                 \
  __builtin_amdgcn_sched_barrier(0);                                          \
  PROC(Scur);

  LOADP(A, g0); ISSW(A);
  __builtin_amdgcn_sched_barrier(0);
  kcur = __builtin_amdgcn_readfirstlane(hA);

  int m = 0;
#pragma unroll 1
  for (; m + 2 <= cnt; m += 2) {
    STEP(A, B, g0 + m + 1);
    STEP(B, A, g0 + m + 2);
  }
  if (m < cnt) { PROC(A); }      // odd tail
  DUMP();                        // final pending delta (skipped if dummy bin)

#undef STEP
#undef PROC
#undef DUMP
#undef ISSW
#undef LOADP

  __syncthreads();

  // phase 2: prefix over bins; wave wv checks t in [wv*19, min(151, +19))
  {
    float SA2 = 0.f, SC2 = 0.f;
    int cnd = 151;
    const int t0 = wv * 19;
    const int t1 = (t0 + 19 < NT_) ? t0 + 19 : NT_;
    for (int tt = 0; tt < t1; ++tt) {
      if (tt < NB1_) {
        SA2 += (float)binAi[tt][lane] * ISCL_;
        SC2 += (float)binCi[tt][lane] * ISCL_;
      }
      if (tt >= t0 && cnd == 151) {
        float mv = (float)tt * DT_ * SA2 - SC2;
        if (mv >= 1.0f) cnd = tt;
      }
    }
    cand[wv][lane] = cnd;
  }
  __syncthreads();
  if (tid < 64) {
    int id = cand[0][tid];
#pragma unroll
    for (int w = 1; w < 8; ++w) id = min(id, cand[w][tid]);
    id = min(id, NT_ - 1);               // forced spike at last timestep
    idx1[((size_t)b << 10) + (jp << 6) + tid] = (uint8_t)id;
  }
}

// ---------------------------------------------------------------------------
// Layer-2: brute force. Block = (b,j), 4 waves split the i-range; lane = t.
// ---------------------------------------------------------------------------
__global__ __launch_bounds__(256) void k_main2(const uint8_t* __restrict__ idx1,
                                               const float* __restrict__ W2,
                                               float* __restrict__ out) {
  __shared__ float wrow[F1_];
  __shared__ float tirow[F1_];
  __shared__ float part[4][3][64];
  const int blk = blockIdx.x;          // 640
  const int b   = blk / 10;
  const int j   = blk - b * 10;
  const int tid = threadIdx.x;
  const int lane = tid & 63, wvv = tid >> 6;

  const float*   w = W2  + (size_t)j * F1_;
  const uint8_t* h = idx1 + (size_t)b * F1_;
  for (int s = tid; s < F1_; s += 256) {
    wrow[s]  = w[s];
    tirow[s] = (float)h[s] * DT_;
  }
  __syncthreads();

  const float tl0 = (float)lane * DT_;
  const float tl1 = (float)(lane + 64) * DT_;
  const float tl2 = (float)(lane + 128) * DT_;
  float m0 = 0.f, m1 = 0.f, m2 = 0.f;
  const int i0 = wvv * 256;
#pragma unroll 4
  for (int i = i0; i < i0 + 256; ++i) {
    float tiv = tirow[i], ww = wrow[i];
    m0 = fmaf(ww, fmaxf(tl0 - tiv, 0.f), m0);
    m1 = fmaf(ww, fmaxf(tl1 - tiv, 0.f), m1);
    m2 = fmaf(ww, fmaxf(tl2 - tiv, 0.f), m2);
  }
  part[wvv][0][lane] = m0;
  part[wvv][1][lane] = m1;
  part[wvv][2][lane] = m2;
  __syncthreads();

  if (wvv == 0) {
    m0 = part[0][0][lane] + part[1][0][lane] + part[2][0][lane] + part[3][0][lane];
    m1 = part[0][1][lane] + part[1][1][lane] + part[2][1][lane] + part[3][1][lane];
    m2 = part[0][2][lane] + part[1][2][lane] + part[2][2][lane] + part[3][2][lane];
    unsigned long long b0 = __ballot(m0 >= 1.0f);
    unsigned long long b1 = __ballot(m1 >= 1.0f);
    unsigned long long b2 = __ballot(m2 >= 1.0f);
    b2 &= (1ull << 23) - 1;            // t <= 150
    b2 |= (1ull << 22);                // forced spike at t = 150
    int tres;
    if (b0)      tres = __ffsll((long long)b0) - 1;
    else if (b1) tres = 64 + __ffsll((long long)b1) - 1;
    else         tres = 128 + __ffsll((long long)b2) - 1;
    if (lane == 0) out[(size_t)b * F2_ + j] = (float)tres * DT_;
  }
}

}  // namespace

// ---------------------------------------------------------------------------
extern "C" void kernel_launch(void* const* d_in, const int* in_sizes, int n_in,
                              void* d_out, int out_size, void* d_ws, size_t ws_size,
                              hipStream_t stream) {
  const float* ti = (const float*)d_in[0];   // [64][1876]
  const float* W1 = (const float*)d_in[1];   // [1024][1876]
  const float* W2 = (const float*)d_in[2];   // [10][1024]
  float* out = (float*)d_out;                // [64][10]

  char* ws = (char*)d_ws;
  float*    W1T  = (float*)(ws + OFF_W1T);
  uint2*    sPr  = (uint2*)(ws + OFF_PAIR);
  uint32_t* gBp  = (uint32_t*)(ws + OFF_GB);
  uint32_t* gNGp = (uint32_t*)(ws + OFF_GNG);
  uint8_t*  idx1 = (uint8_t*)(ws + OFF_IDX1);

  hipLaunchKernelGGL(k_prep,  dim3(544),  dim3(256), 0, stream, W1, ti, W1T, sPr, gBp, gNGp);
  hipLaunchKernelGGL(k_main1, dim3(1024), dim3(512), 0, stream, sPr, gBp, gNGp, W1T, idx1);
  hipLaunchKernelGGL(k_main2, dim3(640),  dim3(256), 0, stream, idx1, W2, out);
}